// Round 8
// baseline (737.781 us; speedup 1.0000x reference)
//
#include <hip/hip_runtime.h>
#include <hip/hip_bf16.h>
#include <stdint.h>

#define B_ 2
#define S_ 2048
#define HKV_ 8
#define D_ 128

#define KVB 32
#define KTILE_SH 4096        // 8 KB: [ks(8)][hi(2)][key(32)][j(8)] shorts
#define VTILE_SH 4096        // 8 KB: [dt*2+ks2(8)][hi(2)][d(32)][j(8)] shorts
#define LDSBUF 16384         // bytes per staging buffer (K 8 KB + V 8 KB)
#define PLANE4 4194304       // float4 per cache plane

typedef __attribute__((ext_vector_type(8))) short bf16x8;
typedef __attribute__((ext_vector_type(16))) float f32x16;
typedef __attribute__((ext_vector_type(4))) int int4v;

typedef const __attribute__((address_space(1))) void gv_t;
typedef __attribute__((address_space(3))) void lv_t;

__device__ __forceinline__ unsigned pk2(float lo, float hi) {
  unsigned r;
  asm("v_cvt_pk_bf16_f32 %0, %1, %2" : "=v"(r) : "v"(lo), "v"(hi));
  return r;
}
__device__ __forceinline__ void plswap(unsigned& a, unsigned& b) {
  asm volatile("v_permlane32_swap_b32 %0, %1" : "+v"(a), "+v"(b));
}
__device__ __forceinline__ bf16x8 frag4(unsigned a, unsigned b, unsigned c, unsigned d) {
  union { int4v i; bf16x8 v; } u;
  u.i = int4v{(int)a, (int)b, (int)c, (int)d};
  return u.v;
}

// ---------------- cache copy (nt stores: keep LLC for kvc source/images) ----------------

__global__ __launch_bounds__(256)
void copy_kernel(const int4v* __restrict__ src, int4v* __restrict__ dst) {
  const int i = blockIdx.x * 256 + threadIdx.x;   // 524288 threads
#pragma unroll
  for (int j = 0; j < 16; ++j) {
    int64_t idx = (int64_t)j * 524288 + i;
    __builtin_nontemporal_store(src[idx], &dst[idx]);
  }
}

// ------- prep: K,V f32 -> bf16 fragment-linear images + exact fp32 cache scatter -------

__global__ __launch_bounds__(256)
void prep_kernel(const float* __restrict__ K, const float* __restrict__ V,
                 const int* __restrict__ bi, const int* __restrict__ bo,
                 float* __restrict__ kc, float* __restrict__ vc,
                 short* __restrict__ kimg, short* __restrict__ vimg) {
  __shared__ float Vf[KVB * 132];
  const int bid = blockIdx.x;
  const int hg  = bid & 15;          // (b,kvh)
  const int kt  = bid >> 4;          // 0..63
  const int kvh = hg & 7;
  const int b   = hg >> 3;
  const int tid = threadIdx.x;
  const int kv0 = kt * KVB;
  const float* kb = K + (int64_t)b * S_ * 1024 + kvh * 128;
  const float* vb = V + (int64_t)b * S_ * 1024 + kvh * 128;
  short* kimg_t = kimg + (int64_t)(hg * 64 + kt) * KTILE_SH;
  short* vimg_t = vimg + (int64_t)(hg * 64 + kt) * VTILE_SH;
#pragma unroll
  for (int i = 0; i < 4; ++i) {
    int idx = i * 256 + tid;         // 0..1023 float4 slots
    int key = idx >> 5;              // 0..31
    int d0  = (idx & 31) * 4;
    int64_t roff = (int64_t)(kv0 + key) * 1024 + d0;
    float4 kf = *(const float4*)(kb + roff);
    float4 vf = *(const float4*)(vb + roff);
    // cache scatter (exact fp32; overwrites copied slots)
    int tok = b * S_ + kv0 + key;
    int64_t slot = (int64_t)bi[tok] * 128 + bo[tok];
    *(float4*)(kc + slot * 1024 + kvh * 128 + d0) = kf;
    *(float4*)(vc + slot * 1024 + kvh * 128 + d0) = vf;
    // K image, fragment-linear: [d0>>3][key][d0&7]
    unsigned k01 = pk2(kf.x, kf.y), k23 = pk2(kf.z, kf.w);
    int koff = (d0 >> 3) * 256 + key * 8 + (d0 & 7);
    int2 st; st.x = (int)k01; st.y = (int)k23;
    *(int2*)(kimg_t + koff) = st;
    *(float4*)(&Vf[key * 132 + d0]) = vf;
  }
  __syncthreads();
  const int d  = tid & 127;
  const int kg = tid >> 7;           // 0..1, keys k0..k0+15
  const int k0 = kg * 16;
  unsigned uu[8];
#pragma unroll
  for (int i2 = 0; i2 < 8; ++i2)
    uu[i2] = pk2(Vf[(k0 + 2 * i2) * 132 + d], Vf[(k0 + 2 * i2 + 1) * 132 + d]);
  int vbase = ((d >> 5) * 4 + (k0 >> 4) * 2) * 256 + (d & 31) * 8;
  *(int4v*)(vimg_t + vbase)       = int4v{(int)uu[0], (int)uu[1], (int)uu[2], (int)uu[3]};
  *(int4v*)(vimg_t + vbase + 256) = int4v{(int)uu[4], (int)uu[5], (int)uu[6], (int)uu[7]};
}

// ---------------- causal GQA flash attention ----------------
// block = (b,kvh, 32 q rows) x 4 heads; 4 waves. Swapped MFMAs:
//   S^T = mfma(K, Q^T): lane owns col = one (head,q); softmax lane-local.
//   O^T = mfma(V^T, P^T). C/D: col=l&31, row=(r&3)+8*(r>>2)+4*(l>>5).
// Softmax in log2 domain; running shift m carried in the MFMA C-init (s = QK - m).

__global__ __launch_bounds__(256, 5)
void attn_kernel(const float* __restrict__ Q, const short* __restrict__ kimg,
                 const short* __restrict__ vimg, float* __restrict__ O) {
  __shared__ int4v ldsv[2 * LDSBUF / 16];
  char* ldsb = (char*)ldsv;

  const int bid = blockIdx.x;
  const int tid = threadIdx.x;
  const int hg  = bid & 15;          // hg&7 spreads (b,kvh) across XCDs
  const int cc  = 63 - (bid >> 4);   // LPT: longest q-chunks first
  const int kvh = hg & 7;
  const int b   = hg >> 3;

  const int w   = tid >> 6;
  const int l   = tid & 63;
  const int c31 = l & 31;
  const int hi  = l >> 5;
  const int qi  = c31 & 15;
  const int hh  = c31 >> 4;
  const int qoff = cc * 32 + (w & 1) * 16;
  const int qrow = qoff + qi;
  const int h    = kvh * 4 + (w >> 1) * 2 + hh;

  const float qscale = 0.08838834764831845f * 1.4426950408889634f; // 1/sqrt(D)*log2e

  // ---- Q fragments (B-frag: col = (head,q), k = d-slice) ----
  const float* qp = Q + ((int64_t)(b * S_ + qrow)) * 4096 + h * 128;
  bf16x8 qf[8];
#pragma unroll
  for (int ks = 0; ks < 8; ++ks) {
    int d0 = ks * 16 + hi * 8;
    float4 x = *(const float4*)(qp + d0);
    float4 y = *(const float4*)(qp + d0 + 4);
    qf[ks] = frag4(pk2(x.x * qscale, x.y * qscale), pk2(x.z * qscale, x.w * qscale),
                   pk2(y.x * qscale, y.y * qscale), pk2(y.z * qscale, y.w * qscale));
  }

  f32x16 acc[4];
#pragma unroll
  for (int dt = 0; dt < 4; ++dt)
#pragma unroll
    for (int r = 0; r < 16; ++r) acc[dt][r] = 0.f;
  float m = 0.f, lsum = 0.f;    // log2-domain shift; m=0 safe (defer-max bounds p<=2^11)

  const int nkt = cc + 1;
  const short* kimg_b = kimg + (int64_t)(hg * 64) * KTILE_SH;
  const short* vimg_b = vimg + (int64_t)(hg * 64) * VTILE_SH;

#define STAGE(KT, BUF)                                                           \
  do {                                                                           \
    const short* kg_ = kimg_b + (int64_t)(KT) * KTILE_SH;                        \
    const short* vg_ = vimg_b + (int64_t)(KT) * VTILE_SH;                        \
    char* kd_ = ldsb + (BUF) * LDSBUF;                                           \
    char* vd_ = kd_ + 8192;                                                      \
    _Pragma("unroll")                                                            \
    for (int i_ = 0; i_ < 2; ++i_) {                                             \
      int u_ = i_ * 256 + w * 64;                                                \
      __builtin_amdgcn_global_load_lds((gv_t*)(const void*)(kg_ + (u_ + l) * 8), \
                                       (lv_t*)(void*)(kd_ + u_ * 16), 16, 0, 0); \
      __builtin_amdgcn_global_load_lds((gv_t*)(const void*)(vg_ + (u_ + l) * 8), \
                                       (lv_t*)(void*)(vd_ + u_ * 16), 16, 0, 0); \
    }                                                                            \
  } while (0)

  STAGE(0, 0);

  for (int kt = 0; kt < nkt; ++kt) {
    __syncthreads();                  // buf[kt&1] ready; buf[kt&1 ^1] free
    const int cur = kt & 1;
    if (kt + 1 < nkt) STAGE(kt + 1, cur ^ 1);
    const char* kfr = ldsb + cur * LDSBUF + hi * 512 + c31 * 16;
    const char* vfr = kfr + 8192;
    const int kv0 = kt * KVB;

    // ---- S^T = K . Q^T, C-init = -m (folds softmax shift into MFMA) ----
    const float negm = -m;
    f32x16 s;
#pragma unroll
    for (int r = 0; r < 16; ++r) s[r] = negm;
    __builtin_amdgcn_s_setprio(1);
#pragma unroll
    for (int ks = 0; ks < 8; ++ks) {
      bf16x8 kf = *(const bf16x8*)(kfr + ks * 1024);
      s = __builtin_amdgcn_mfma_f32_32x32x16_bf16(kf, qf[ks], s, 0, 0, 0);
    }
    __builtin_amdgcn_s_setprio(0);

    // ---- hoist V fragment reads: overlap with softmax VALU below ----
    bf16x8 vfrag[8];
#pragma unroll
    for (int i = 0; i < 8; ++i) vfrag[i] = *(const bf16x8*)(vfr + i * 1024);

    // ---- causal mask (boundary tiles only) ----
    if (kv0 + 31 > qoff) {
#pragma unroll
      for (int r = 0; r < 16; ++r) {
        int key = kv0 + (r & 3) + 8 * (r >> 2) + 4 * hi;
        if (key > qrow) s[r] = -1e30f;
      }
    }

    // ---- lane-local online softmax (log2 domain, defer-max THR=11) ----
    float a0 = fmaxf(s[0], s[1]),   a1 = fmaxf(s[2], s[3]);
    float a2 = fmaxf(s[4], s[5]),   a3 = fmaxf(s[6], s[7]);
    float a4 = fmaxf(s[8], s[9]),   a5 = fmaxf(s[10], s[11]);
    float a6 = fmaxf(s[12], s[13]), a7 = fmaxf(s[14], s[15]);
    a0 = fmaxf(a0, a1); a2 = fmaxf(a2, a3); a4 = fmaxf(a4, a5); a6 = fmaxf(a6, a7);
    float qm = fmaxf(fmaxf(a0, a2), fmaxf(a4, a6));   // = tile max - m
    qm = fmaxf(qm, __shfl_xor(qm, 32));               // partner lane (same q)
    if (__any(qm > 11.0f)) {
      float dsh = fmaxf(qm, 0.f);
      float al = exp2f(-dsh);
      m += dsh; lsum *= al;
#pragma unroll
      for (int r = 0; r < 16; ++r) s[r] -= dsh;
#pragma unroll
      for (int dt = 0; dt < 4; ++dt)
#pragma unroll
        for (int r = 0; r < 16; ++r) acc[dt][r] *= al;
    }
    float p[16];
#pragma unroll
    for (int r = 0; r < 16; ++r) p[r] = exp2f(s[r]);
    float b0 = (p[0] + p[1]) + (p[2] + p[3]);
    float b1 = (p[4] + p[5]) + (p[6] + p[7]);
    float b2 = (p[8] + p[9]) + (p[10] + p[11]);
    float b3 = (p[12] + p[13]) + (p[14] + p[15]);
    lsum += (b0 + b1) + (b2 + b3);

    // ---- P -> bf16 B-frags via cvt_pk + permlane32_swap (no LDS) ----
    unsigned u0 = pk2(p[0], p[1]),   u1 = pk2(p[2], p[3]);
    unsigned u2 = pk2(p[4], p[5]),   u3 = pk2(p[6], p[7]);
    unsigned u4 = pk2(p[8], p[9]),   u5 = pk2(p[10], p[11]);
    unsigned u6 = pk2(p[12], p[13]), u7 = pk2(p[14], p[15]);
    plswap(u0, u2); plswap(u1, u3);          // keys 0..15
    plswap(u4, u6); plswap(u5, u7);          // keys 16..31
    bf16x8 pf0 = frag4(u0, u1, u2, u3);
    bf16x8 pf1 = frag4(u4, u5, u6, u7);

    // ---- O^T += V^T . P^T ----
    __builtin_amdgcn_s_setprio(1);
#pragma unroll
    for (int ks2 = 0; ks2 < 2; ++ks2) {
      bf16x8 pf = ks2 ? pf1 : pf0;
#pragma unroll
      for (int dt = 0; dt < 4; ++dt)
        acc[dt] = __builtin_amdgcn_mfma_f32_32x32x16_bf16(vfrag[dt * 2 + ks2], pf,
                                                          acc[dt], 0, 0, 0);
    }
    __builtin_amdgcn_s_setprio(0);
  }
#undef STAGE

  // ---- epilogue: combine partner l, transpose O^T -> O via LDS, store ----
  float lt = lsum + __shfl_xor(lsum, 32);
  float inv = 1.0f / lt;
  __syncthreads();                           // staging buffers dead now
  float* scr = (float*)ldsb + w * (32 * 33);
  float* ob = O + (int64_t)(b * S_) * 4096;
#pragma unroll
  for (int dt = 0; dt < 4; ++dt) {
#pragma unroll
    for (int r = 0; r < 16; ++r) {
      int crow = (r & 3) + 8 * (r >> 2) + 4 * hi;
      scr[c31 * 33 + crow] = acc[dt][r] * inv;   // scr[col][d']
    }
    asm volatile("" ::: "memory");
#pragma unroll
    for (int rr = 0; rr < 16; ++rr) {
      int col = rr * 2 + hi;
      float val = scr[col * 33 + c31];
      int qi2 = col & 15, hh2 = col >> 4;
      int qq = cc * 32 + (w & 1) * 16 + qi2;
      int h2 = kvh * 4 + (w >> 1) * 2 + hh2;
      ob[(int64_t)qq * 4096 + h2 * 128 + dt * 32 + c31] = val;
    }
    asm volatile("" ::: "memory");
  }
}

extern "C" void kernel_launch(void* const* d_in, const int* in_sizes, int n_in,
                              void* d_out, int out_size, void* d_ws, size_t ws_size,
                              hipStream_t stream) {
  const float* Q   = (const float*)d_in[0];
  const float* K   = (const float*)d_in[1];
  const float* V   = (const float*)d_in[2];
  const float* kvc = (const float*)d_in[3];
  const int*   bi  = (const int*)d_in[4];
  const int*   bo  = (const int*)d_in[5];
  // d_in[6] = attn_bias: exactly the causal mask; applied analytically.

  float* out = (float*)d_out;
  float* kc = out + (int64_t)B_ * S_ * 32 * 128;         // +16777216
  float* vc = kc + (int64_t)128 * 128 * HKV_ * D_;       // +16777216

  short* kimg = (short*)d_ws;                            // 1024 tiles * 8 KB
  short* vimg = kimg + (int64_t)1024 * KTILE_SH;         // 1024 tiles * 8 KB

  // 1) full cache copy (nt stores), both planes
  hipLaunchKernelGGL(copy_kernel, dim3(2048), dim3(256), 0, stream,
                     (const int4v*)kvc, (int4v*)kc);
  // 2) bf16 fragment-linear K/V images + exact fp32 scatter over the copy
  hipLaunchKernelGGL(prep_kernel, dim3(1024), dim3(256), 0, stream,
                     K, V, bi, bo, kc, vc, kimg, vimg);
  // 3) causal GQA attention
  hipLaunchKernelGGL(attn_kernel, dim3(1024), dim3(256), 0, stream,
                     Q, kimg, vimg, out);
}

// Round 9
// 532.157 us; speedup vs baseline: 1.3864x; 1.3864x over previous
//
#include <hip/hip_runtime.h>
#include <hip/hip_bf16.h>
#include <stdint.h>

#define B_ 2
#define S_ 2048
#define HKV_ 8
#define D_ 128

#define KVB 32
#define KTILE_SH 4096        // 8 KB: [ks(8)][hi(2)][key(32)][j(8)] shorts
#define VTILE_SH 4096        // 8 KB: [dt*2+ks2(8)][hi(2)][d(32)][j(8)] shorts
#define LDSBUF 16384         // bytes per staging buffer (K 8 KB + V 8 KB)
#define PLANE4 4194304       // float4 per cache plane

typedef __attribute__((ext_vector_type(8))) short bf16x8;
typedef __attribute__((ext_vector_type(16))) float f32x16;
typedef __attribute__((ext_vector_type(4))) int int4v;

typedef const __attribute__((address_space(1))) void gv_t;
typedef __attribute__((address_space(3))) void lv_t;

__device__ __forceinline__ unsigned pk2(float lo, float hi) {
  unsigned r;
  asm("v_cvt_pk_bf16_f32 %0, %1, %2" : "=v"(r) : "v"(lo), "v"(hi));
  return r;
}
__device__ __forceinline__ void plswap(unsigned& a, unsigned& b) {
  asm volatile("v_permlane32_swap_b32 %0, %1" : "+v"(a), "+v"(b));
}
__device__ __forceinline__ bf16x8 frag4(unsigned a, unsigned b, unsigned c, unsigned d) {
  union { int4v i; bf16x8 v; } u;
  u.i = int4v{(int)a, (int)b, (int)c, (int)d};
  return u.v;
}

// ---------------- cache copy (nt stores: keep LLC for kvc source/images) ----------------

__global__ __launch_bounds__(256)
void copy_kernel(const int4v* __restrict__ src, int4v* __restrict__ dst) {
  const int i = blockIdx.x * 256 + threadIdx.x;   // 524288 threads
#pragma unroll
  for (int j = 0; j < 16; ++j) {
    int64_t idx = (int64_t)j * 524288 + i;
    __builtin_nontemporal_store(src[idx], &dst[idx]);
  }
}

// ------- prep: K,V f32 -> bf16 fragment-linear images + exact fp32 cache scatter -------

__global__ __launch_bounds__(256)
void prep_kernel(const float* __restrict__ K, const float* __restrict__ V,
                 const int* __restrict__ bi, const int* __restrict__ bo,
                 float* __restrict__ kc, float* __restrict__ vc,
                 short* __restrict__ kimg, short* __restrict__ vimg) {
  __shared__ float Vf[KVB * 132];
  const int bid = blockIdx.x;
  const int hg  = bid & 15;          // (b,kvh)
  const int kt  = bid >> 4;          // 0..63
  const int kvh = hg & 7;
  const int b   = hg >> 3;
  const int tid = threadIdx.x;
  const int kv0 = kt * KVB;
  const float* kb = K + (int64_t)b * S_ * 1024 + kvh * 128;
  const float* vb = V + (int64_t)b * S_ * 1024 + kvh * 128;
  short* kimg_t = kimg + (int64_t)(hg * 64 + kt) * KTILE_SH;
  short* vimg_t = vimg + (int64_t)(hg * 64 + kt) * VTILE_SH;
#pragma unroll
  for (int i = 0; i < 4; ++i) {
    int idx = i * 256 + tid;         // 0..1023 float4 slots
    int key = idx >> 5;              // 0..31
    int d0  = (idx & 31) * 4;
    int64_t roff = (int64_t)(kv0 + key) * 1024 + d0;
    float4 kf = *(const float4*)(kb + roff);
    float4 vf = *(const float4*)(vb + roff);
    // cache scatter (exact fp32; overwrites copied slots)
    int tok = b * S_ + kv0 + key;
    int64_t slot = (int64_t)bi[tok] * 128 + bo[tok];
    *(float4*)(kc + slot * 1024 + kvh * 128 + d0) = kf;
    *(float4*)(vc + slot * 1024 + kvh * 128 + d0) = vf;
    // K image, fragment-linear: [d0>>3][key][d0&7]
    unsigned k01 = pk2(kf.x, kf.y), k23 = pk2(kf.z, kf.w);
    int koff = (d0 >> 3) * 256 + key * 8 + (d0 & 7);
    int2 st; st.x = (int)k01; st.y = (int)k23;
    *(int2*)(kimg_t + koff) = st;
    *(float4*)(&Vf[key * 132 + d0]) = vf;
  }
  __syncthreads();
  const int d  = tid & 127;
  const int kg = tid >> 7;           // 0..1, keys k0..k0+15
  const int k0 = kg * 16;
  unsigned uu[8];
#pragma unroll
  for (int i2 = 0; i2 < 8; ++i2)
    uu[i2] = pk2(Vf[(k0 + 2 * i2) * 132 + d], Vf[(k0 + 2 * i2 + 1) * 132 + d]);
  int vbase = ((d >> 5) * 4 + (k0 >> 4) * 2) * 256 + (d & 31) * 8;
  *(int4v*)(vimg_t + vbase)       = int4v{(int)uu[0], (int)uu[1], (int)uu[2], (int)uu[3]};
  *(int4v*)(vimg_t + vbase + 256) = int4v{(int)uu[4], (int)uu[5], (int)uu[6], (int)uu[7]};
}

// ---------------- causal GQA flash attention ----------------
// block = (b,kvh, 32 q rows) x 4 heads; 4 waves. Swapped MFMAs:
//   S^T = mfma(K, Q^T): lane owns col = one (head,q); softmax lane-local.
//   O^T = mfma(V^T, P^T). C/D: col=l&31, row=(r&3)+8*(r>>2)+4*(l>>5).
// Softmax in log2 domain; running shift m carried in the MFMA C-init (s = QK - m).
// NOTE: __launch_bounds__ 2nd arg MUST stay <=4: (256,5) squeezed the unified
// VGPR/AGPR budget and spilled acc to scratch (R8: FETCH 46MB->1.1GB, 6x slower).

__global__ __launch_bounds__(256, 4)
void attn_kernel(const float* __restrict__ Q, const short* __restrict__ kimg,
                 const short* __restrict__ vimg, float* __restrict__ O) {
  __shared__ int4v ldsv[2 * LDSBUF / 16];
  char* ldsb = (char*)ldsv;

  const int bid = blockIdx.x;
  const int tid = threadIdx.x;
  const int hg  = bid & 15;          // hg&7 spreads (b,kvh) across XCDs
  const int cc  = 63 - (bid >> 4);   // LPT: longest q-chunks first
  const int kvh = hg & 7;
  const int b   = hg >> 3;

  const int w   = tid >> 6;
  const int l   = tid & 63;
  const int c31 = l & 31;
  const int hi  = l >> 5;
  const int qi  = c31 & 15;
  const int hh  = c31 >> 4;
  const int qoff = cc * 32 + (w & 1) * 16;
  const int qrow = qoff + qi;
  const int h    = kvh * 4 + (w >> 1) * 2 + hh;

  const float qscale = 0.08838834764831845f * 1.4426950408889634f; // 1/sqrt(D)*log2e

  // ---- Q fragments (B-frag: col = (head,q), k = d-slice) ----
  const float* qp = Q + ((int64_t)(b * S_ + qrow)) * 4096 + h * 128;
  bf16x8 qf[8];
#pragma unroll
  for (int ks = 0; ks < 8; ++ks) {
    int d0 = ks * 16 + hi * 8;
    float4 x = *(const float4*)(qp + d0);
    float4 y = *(const float4*)(qp + d0 + 4);
    qf[ks] = frag4(pk2(x.x * qscale, x.y * qscale), pk2(x.z * qscale, x.w * qscale),
                   pk2(y.x * qscale, y.y * qscale), pk2(y.z * qscale, y.w * qscale));
  }

  f32x16 acc[4];
#pragma unroll
  for (int dt = 0; dt < 4; ++dt)
#pragma unroll
    for (int r = 0; r < 16; ++r) acc[dt][r] = 0.f;
  float m = 0.f, lsum = 0.f;    // log2-domain shift; m=0 safe (defer-max bounds p<=2^11)

  const int nkt = cc + 1;
  const short* kimg_b = kimg + (int64_t)(hg * 64) * KTILE_SH;
  const short* vimg_b = vimg + (int64_t)(hg * 64) * VTILE_SH;

#define STAGE(KT, BUF)                                                           \
  do {                                                                           \
    const short* kg_ = kimg_b + (int64_t)(KT) * KTILE_SH;                        \
    const short* vg_ = vimg_b + (int64_t)(KT) * VTILE_SH;                        \
    char* kd_ = ldsb + (BUF) * LDSBUF;                                           \
    char* vd_ = kd_ + 8192;                                                      \
    _Pragma("unroll")                                                            \
    for (int i_ = 0; i_ < 2; ++i_) {                                             \
      int u_ = i_ * 256 + w * 64;                                                \
      __builtin_amdgcn_global_load_lds((gv_t*)(const void*)(kg_ + (u_ + l) * 8), \
                                       (lv_t*)(void*)(kd_ + u_ * 16), 16, 0, 0); \
      __builtin_amdgcn_global_load_lds((gv_t*)(const void*)(vg_ + (u_ + l) * 8), \
                                       (lv_t*)(void*)(vd_ + u_ * 16), 16, 0, 0); \
    }                                                                            \
  } while (0)

  STAGE(0, 0);

  for (int kt = 0; kt < nkt; ++kt) {
    __syncthreads();                  // buf[kt&1] ready; buf[kt&1 ^1] free
    const int cur = kt & 1;
    if (kt + 1 < nkt) STAGE(kt + 1, cur ^ 1);
    const char* kfr = ldsb + cur * LDSBUF + hi * 512 + c31 * 16;
    const char* vfr = kfr + 8192;
    const int kv0 = kt * KVB;

    // ---- S^T = K . Q^T, C-init = -m (folds softmax shift into MFMA) ----
    const float negm = -m;
    f32x16 s;
#pragma unroll
    for (int r = 0; r < 16; ++r) s[r] = negm;
    __builtin_amdgcn_s_setprio(1);
#pragma unroll
    for (int ks = 0; ks < 8; ++ks) {
      bf16x8 kf = *(const bf16x8*)(kfr + ks * 1024);
      s = __builtin_amdgcn_mfma_f32_32x32x16_bf16(kf, qf[ks], s, 0, 0, 0);
    }
    __builtin_amdgcn_s_setprio(0);

    // ---- hoist V fragment reads: overlap with softmax VALU below ----
    bf16x8 vfrag[8];
#pragma unroll
    for (int i = 0; i < 8; ++i) vfrag[i] = *(const bf16x8*)(vfr + i * 1024);

    // ---- causal mask (boundary tiles only) ----
    if (kv0 + 31 > qoff) {
#pragma unroll
      for (int r = 0; r < 16; ++r) {
        int key = kv0 + (r & 3) + 8 * (r >> 2) + 4 * hi;
        if (key > qrow) s[r] = -1e30f;
      }
    }

    // ---- lane-local online softmax (log2 domain, defer-max THR=11) ----
    float a0 = fmaxf(s[0], s[1]),   a1 = fmaxf(s[2], s[3]);
    float a2 = fmaxf(s[4], s[5]),   a3 = fmaxf(s[6], s[7]);
    float a4 = fmaxf(s[8], s[9]),   a5 = fmaxf(s[10], s[11]);
    float a6 = fmaxf(s[12], s[13]), a7 = fmaxf(s[14], s[15]);
    a0 = fmaxf(a0, a1); a2 = fmaxf(a2, a3); a4 = fmaxf(a4, a5); a6 = fmaxf(a6, a7);
    float qm = fmaxf(fmaxf(a0, a2), fmaxf(a4, a6));   // = tile max - m
    qm = fmaxf(qm, __shfl_xor(qm, 32));               // partner lane (same q)
    if (__any(qm > 11.0f)) {
      float dsh = fmaxf(qm, 0.f);
      float al = exp2f(-dsh);
      m += dsh; lsum *= al;
#pragma unroll
      for (int r = 0; r < 16; ++r) s[r] -= dsh;
#pragma unroll
      for (int dt = 0; dt < 4; ++dt)
#pragma unroll
        for (int r = 0; r < 16; ++r) acc[dt][r] *= al;
    }
    float p[16];
#pragma unroll
    for (int r = 0; r < 16; ++r) p[r] = exp2f(s[r]);
    float b0 = (p[0] + p[1]) + (p[2] + p[3]);
    float b1 = (p[4] + p[5]) + (p[6] + p[7]);
    float b2 = (p[8] + p[9]) + (p[10] + p[11]);
    float b3 = (p[12] + p[13]) + (p[14] + p[15]);
    lsum += (b0 + b1) + (b2 + b3);

    // ---- P -> bf16 B-frags via cvt_pk + permlane32_swap (no LDS) ----
    unsigned u0 = pk2(p[0], p[1]),   u1 = pk2(p[2], p[3]);
    unsigned u2 = pk2(p[4], p[5]),   u3 = pk2(p[6], p[7]);
    unsigned u4 = pk2(p[8], p[9]),   u5 = pk2(p[10], p[11]);
    unsigned u6 = pk2(p[12], p[13]), u7 = pk2(p[14], p[15]);
    plswap(u0, u2); plswap(u1, u3);          // keys 0..15
    plswap(u4, u6); plswap(u5, u7);          // keys 16..31
    bf16x8 pf0 = frag4(u0, u1, u2, u3);
    bf16x8 pf1 = frag4(u4, u5, u6, u7);

    // ---- O^T += V^T . P^T ----
    __builtin_amdgcn_s_setprio(1);
#pragma unroll
    for (int ks2 = 0; ks2 < 2; ++ks2) {
      bf16x8 pf = ks2 ? pf1 : pf0;
#pragma unroll
      for (int dt = 0; dt < 4; ++dt)
        acc[dt] = __builtin_amdgcn_mfma_f32_32x32x16_bf16(vfrag[dt * 2 + ks2], pf,
                                                          acc[dt], 0, 0, 0);
    }
    __builtin_amdgcn_s_setprio(0);
  }
#undef STAGE

  // ---- epilogue: combine partner l, transpose O^T -> O via LDS, store ----
  float lt = lsum + __shfl_xor(lsum, 32);
  float inv = 1.0f / lt;
  __syncthreads();                           // staging buffers dead now
  float* scr = (float*)ldsb + w * (32 * 33);
  float* ob = O + (int64_t)(b * S_) * 4096;
#pragma unroll
  for (int dt = 0; dt < 4; ++dt) {
#pragma unroll
    for (int r = 0; r < 16; ++r) {
      int crow = (r & 3) + 8 * (r >> 2) + 4 * hi;
      scr[c31 * 33 + crow] = acc[dt][r] * inv;   // scr[col][d']
    }
    asm volatile("" ::: "memory");
#pragma unroll
    for (int rr = 0; rr < 16; ++rr) {
      int col = rr * 2 + hi;
      float val = scr[col * 33 + c31];
      int qi2 = col & 15, hh2 = col >> 4;
      int qq = cc * 32 + (w & 1) * 16 + qi2;
      int h2 = kvh * 4 + (w >> 1) * 2 + hh2;
      ob[(int64_t)qq * 4096 + h2 * 128 + dt * 32 + c31] = val;
    }
    asm volatile("" ::: "memory");
  }
}

extern "C" void kernel_launch(void* const* d_in, const int* in_sizes, int n_in,
                              void* d_out, int out_size, void* d_ws, size_t ws_size,
                              hipStream_t stream) {
  const float* Q   = (const float*)d_in[0];
  const float* K   = (const float*)d_in[1];
  const float* V   = (const float*)d_in[2];
  const float* kvc = (const float*)d_in[3];
  const int*   bi  = (const int*)d_in[4];
  const int*   bo  = (const int*)d_in[5];
  // d_in[6] = attn_bias: exactly the causal mask; applied analytically.

  float* out = (float*)d_out;
  float* kc = out + (int64_t)B_ * S_ * 32 * 128;         // +16777216
  float* vc = kc + (int64_t)128 * 128 * HKV_ * D_;       // +16777216

  short* kimg = (short*)d_ws;                            // 1024 tiles * 8 KB
  short* vimg = kimg + (int64_t)1024 * KTILE_SH;         // 1024 tiles * 8 KB

  // 1) full cache copy (nt stores), both planes
  hipLaunchKernelGGL(copy_kernel, dim3(2048), dim3(256), 0, stream,
                     (const int4v*)kvc, (int4v*)kc);
  // 2) bf16 fragment-linear K/V images + exact fp32 scatter over the copy
  hipLaunchKernelGGL(prep_kernel, dim3(1024), dim3(256), 0, stream,
                     K, V, bi, bo, kc, vc, kimg, vimg);
  // 3) causal GQA attention
  hipLaunchKernelGGL(attn_kernel, dim3(1024), dim3(256), 0, stream,
                     Q, kimg, vimg, out);
}

// Round 10
// 200.837 us; speedup vs baseline: 3.6735x; 2.6497x over previous
//
#include <hip/hip_runtime.h>
#include <hip/hip_bf16.h>
#include <stdint.h>

#define B_ 2
#define S_ 2048
#define HKV_ 8
#define D_ 128

#define KVB 32
#define KTILE_SH 4096        // 8 KB: [ks(8)][hi(2)][key(32)][j(8)] shorts
#define VTILE_SH 4096        // 8 KB: [dt*2+ks2(8)][hi(2)][d(32)][j(8)] shorts
#define LDSBUF 16384         // bytes per staging buffer (K 8 KB + V 8 KB)
#define PLANE4 4194304       // float4 per cache plane

typedef __attribute__((ext_vector_type(8))) short bf16x8;
typedef __attribute__((ext_vector_type(16))) float f32x16;
typedef __attribute__((ext_vector_type(4))) int int4v;

typedef const __attribute__((address_space(1))) void gv_t;
typedef __attribute__((address_space(3))) void lv_t;

__device__ __forceinline__ unsigned pk2(float lo, float hi) {
  unsigned r;
  asm("v_cvt_pk_bf16_f32 %0, %1, %2" : "=v"(r) : "v"(lo), "v"(hi));
  return r;
}
__device__ __forceinline__ void plswap(unsigned& a, unsigned& b) {
  asm volatile("v_permlane32_swap_b32 %0, %1" : "+v"(a), "+v"(b));
}
__device__ __forceinline__ bf16x8 frag4(unsigned a, unsigned b, unsigned c, unsigned d) {
  union { int4v i; bf16x8 v; } u;
  u.i = int4v{(int)a, (int)b, (int)c, (int)d};
  return u.v;
}

// ---------------- cache copy (nt stores: keep LLC for kvc source/images) ----------------

__global__ __launch_bounds__(256)
void copy_kernel(const int4v* __restrict__ src, int4v* __restrict__ dst) {
  const int i = blockIdx.x * 256 + threadIdx.x;   // 524288 threads
#pragma unroll
  for (int j = 0; j < 16; ++j) {
    int64_t idx = (int64_t)j * 524288 + i;
    __builtin_nontemporal_store(src[idx], &dst[idx]);
  }
}

// ------- prep: K,V f32 -> bf16 fragment-linear images + exact fp32 cache scatter -------

__global__ __launch_bounds__(256)
void prep_kernel(const float* __restrict__ K, const float* __restrict__ V,
                 const int* __restrict__ bi, const int* __restrict__ bo,
                 float* __restrict__ kc, float* __restrict__ vc,
                 short* __restrict__ kimg, short* __restrict__ vimg) {
  __shared__ float Vf[KVB * 132];
  const int bid = blockIdx.x;
  const int hg  = bid & 15;          // (b,kvh)
  const int kt  = bid >> 4;          // 0..63
  const int kvh = hg & 7;
  const int b   = hg >> 3;
  const int tid = threadIdx.x;
  const int kv0 = kt * KVB;
  const float* kb = K + (int64_t)b * S_ * 1024 + kvh * 128;
  const float* vb = V + (int64_t)b * S_ * 1024 + kvh * 128;
  short* kimg_t = kimg + (int64_t)(hg * 64 + kt) * KTILE_SH;
  short* vimg_t = vimg + (int64_t)(hg * 64 + kt) * VTILE_SH;
#pragma unroll
  for (int i = 0; i < 4; ++i) {
    int idx = i * 256 + tid;         // 0..1023 float4 slots
    int key = idx >> 5;              // 0..31
    int d0  = (idx & 31) * 4;
    int64_t roff = (int64_t)(kv0 + key) * 1024 + d0;
    float4 kf = *(const float4*)(kb + roff);
    float4 vf = *(const float4*)(vb + roff);
    // cache scatter (exact fp32; overwrites copied slots)
    int tok = b * S_ + kv0 + key;
    int64_t slot = (int64_t)bi[tok] * 128 + bo[tok];
    *(float4*)(kc + slot * 1024 + kvh * 128 + d0) = kf;
    *(float4*)(vc + slot * 1024 + kvh * 128 + d0) = vf;
    // K image, fragment-linear: [d0>>3][key][d0&7]
    unsigned k01 = pk2(kf.x, kf.y), k23 = pk2(kf.z, kf.w);
    int koff = (d0 >> 3) * 256 + key * 8 + (d0 & 7);
    int2 st; st.x = (int)k01; st.y = (int)k23;
    *(int2*)(kimg_t + koff) = st;
    *(float4*)(&Vf[key * 132 + d0]) = vf;
  }
  __syncthreads();
  const int d  = tid & 127;
  const int kg = tid >> 7;           // 0..1, keys k0..k0+15
  const int k0 = kg * 16;
  unsigned uu[8];
#pragma unroll
  for (int i2 = 0; i2 < 8; ++i2)
    uu[i2] = pk2(Vf[(k0 + 2 * i2) * 132 + d], Vf[(k0 + 2 * i2 + 1) * 132 + d]);
  int vbase = ((d >> 5) * 4 + (k0 >> 4) * 2) * 256 + (d & 31) * 8;
  *(int4v*)(vimg_t + vbase)       = int4v{(int)uu[0], (int)uu[1], (int)uu[2], (int)uu[3]};
  *(int4v*)(vimg_t + vbase + 256) = int4v{(int)uu[4], (int)uu[5], (int)uu[6], (int)uu[7]};
}

// ---------------- causal GQA flash attention ----------------
// block = (b,kvh, 32 q rows) x 4 heads; 4 waves. Swapped MFMAs:
//   S^T = mfma(K, Q^T): lane owns col = one (head,q); softmax lane-local.
//   O^T = mfma(V^T, P^T). C/D: col=l&31, row=(r&3)+8*(r>>2)+4*(l>>5).
// Softmax in log2 domain; running shift m carried in the MFMA C-init (s = QK - m).
// REGISTER BUDGET: body needs ~165 regs/wave (qf 32 + acc 64 + vfrag 32 + s/p 16
// + addressing). (256,3) gives 512/3=170 -> fits. (256,4)=128 SPILLS to scratch
// (R9: FETCH 620MB, 4x slower). (256,5)=102 spills worse (R8: 1.1GB). Keep 3.

__global__ __launch_bounds__(256, 3)
void attn_kernel(const float* __restrict__ Q, const short* __restrict__ kimg,
                 const short* __restrict__ vimg, float* __restrict__ O) {
  __shared__ int4v ldsv[2 * LDSBUF / 16];
  char* ldsb = (char*)ldsv;

  const int bid = blockIdx.x;
  const int tid = threadIdx.x;
  const int hg  = bid & 15;          // hg&7 spreads (b,kvh) across XCDs
  const int cc  = 63 - (bid >> 4);   // LPT: longest q-chunks first
  const int kvh = hg & 7;
  const int b   = hg >> 3;

  const int w   = tid >> 6;
  const int l   = tid & 63;
  const int c31 = l & 31;
  const int hi  = l >> 5;
  const int qi  = c31 & 15;
  const int hh  = c31 >> 4;
  const int qoff = cc * 32 + (w & 1) * 16;
  const int qrow = qoff + qi;
  const int h    = kvh * 4 + (w >> 1) * 2 + hh;

  const float qscale = 0.08838834764831845f * 1.4426950408889634f; // 1/sqrt(D)*log2e

  // ---- Q fragments (B-frag: col = (head,q), k = d-slice) ----
  const float* qp = Q + ((int64_t)(b * S_ + qrow)) * 4096 + h * 128;
  bf16x8 qf[8];
#pragma unroll
  for (int ks = 0; ks < 8; ++ks) {
    int d0 = ks * 16 + hi * 8;
    float4 x = *(const float4*)(qp + d0);
    float4 y = *(const float4*)(qp + d0 + 4);
    qf[ks] = frag4(pk2(x.x * qscale, x.y * qscale), pk2(x.z * qscale, x.w * qscale),
                   pk2(y.x * qscale, y.y * qscale), pk2(y.z * qscale, y.w * qscale));
  }

  f32x16 acc[4];
#pragma unroll
  for (int dt = 0; dt < 4; ++dt)
#pragma unroll
    for (int r = 0; r < 16; ++r) acc[dt][r] = 0.f;
  float m = 0.f, lsum = 0.f;    // log2-domain shift; m=0 safe (defer-max bounds p<=2^11)

  const int nkt = cc + 1;
  const short* kimg_b = kimg + (int64_t)(hg * 64) * KTILE_SH;
  const short* vimg_b = vimg + (int64_t)(hg * 64) * VTILE_SH;

#define STAGE(KT, BUF)                                                           \
  do {                                                                           \
    const short* kg_ = kimg_b + (int64_t)(KT) * KTILE_SH;                        \
    const short* vg_ = vimg_b + (int64_t)(KT) * VTILE_SH;                        \
    char* kd_ = ldsb + (BUF) * LDSBUF;                                           \
    char* vd_ = kd_ + 8192;                                                      \
    _Pragma("unroll")                                                            \
    for (int i_ = 0; i_ < 2; ++i_) {                                             \
      int u_ = i_ * 256 + w * 64;                                                \
      __builtin_amdgcn_global_load_lds((gv_t*)(const void*)(kg_ + (u_ + l) * 8), \
                                       (lv_t*)(void*)(kd_ + u_ * 16), 16, 0, 0); \
      __builtin_amdgcn_global_load_lds((gv_t*)(const void*)(vg_ + (u_ + l) * 8), \
                                       (lv_t*)(void*)(vd_ + u_ * 16), 16, 0, 0); \
    }                                                                            \
  } while (0)

  STAGE(0, 0);

  for (int kt = 0; kt < nkt; ++kt) {
    __syncthreads();                  // buf[kt&1] ready; buf[kt&1 ^1] free
    const int cur = kt & 1;
    if (kt + 1 < nkt) STAGE(kt + 1, cur ^ 1);
    const char* kfr = ldsb + cur * LDSBUF + hi * 512 + c31 * 16;
    const char* vfr = kfr + 8192;
    const int kv0 = kt * KVB;

    // ---- S^T = K . Q^T, C-init = -m (folds softmax shift into MFMA) ----
    const float negm = -m;
    f32x16 s;
#pragma unroll
    for (int r = 0; r < 16; ++r) s[r] = negm;
    __builtin_amdgcn_s_setprio(1);
#pragma unroll
    for (int ks = 0; ks < 8; ++ks) {
      bf16x8 kf = *(const bf16x8*)(kfr + ks * 1024);
      s = __builtin_amdgcn_mfma_f32_32x32x16_bf16(kf, qf[ks], s, 0, 0, 0);
    }
    __builtin_amdgcn_s_setprio(0);

    // ---- hoist V fragment reads: overlap with softmax VALU below ----
    bf16x8 vfrag[8];
#pragma unroll
    for (int i = 0; i < 8; ++i) vfrag[i] = *(const bf16x8*)(vfr + i * 1024);

    // ---- causal mask (boundary tiles only) ----
    if (kv0 + 31 > qoff) {
#pragma unroll
      for (int r = 0; r < 16; ++r) {
        int key = kv0 + (r & 3) + 8 * (r >> 2) + 4 * hi;
        if (key > qrow) s[r] = -1e30f;
      }
    }

    // ---- lane-local online softmax (log2 domain, defer-max THR=11) ----
    float a0 = fmaxf(s[0], s[1]),   a1 = fmaxf(s[2], s[3]);
    float a2 = fmaxf(s[4], s[5]),   a3 = fmaxf(s[6], s[7]);
    float a4 = fmaxf(s[8], s[9]),   a5 = fmaxf(s[10], s[11]);
    float a6 = fmaxf(s[12], s[13]), a7 = fmaxf(s[14], s[15]);
    a0 = fmaxf(a0, a1); a2 = fmaxf(a2, a3); a4 = fmaxf(a4, a5); a6 = fmaxf(a6, a7);
    float qm = fmaxf(fmaxf(a0, a2), fmaxf(a4, a6));   // = tile max - m
    qm = fmaxf(qm, __shfl_xor(qm, 32));               // partner lane (same q)
    if (__any(qm > 11.0f)) {
      float dsh = fmaxf(qm, 0.f);
      float al = exp2f(-dsh);
      m += dsh; lsum *= al;
#pragma unroll
      for (int r = 0; r < 16; ++r) s[r] -= dsh;
#pragma unroll
      for (int dt = 0; dt < 4; ++dt)
#pragma unroll
        for (int r = 0; r < 16; ++r) acc[dt][r] *= al;
    }
    float p[16];
#pragma unroll
    for (int r = 0; r < 16; ++r) p[r] = exp2f(s[r]);
    float b0 = (p[0] + p[1]) + (p[2] + p[3]);
    float b1 = (p[4] + p[5]) + (p[6] + p[7]);
    float b2 = (p[8] + p[9]) + (p[10] + p[11]);
    float b3 = (p[12] + p[13]) + (p[14] + p[15]);
    lsum += (b0 + b1) + (b2 + b3);

    // ---- P -> bf16 B-frags via cvt_pk + permlane32_swap (no LDS) ----
    unsigned u0 = pk2(p[0], p[1]),   u1 = pk2(p[2], p[3]);
    unsigned u2 = pk2(p[4], p[5]),   u3 = pk2(p[6], p[7]);
    unsigned u4 = pk2(p[8], p[9]),   u5 = pk2(p[10], p[11]);
    unsigned u6 = pk2(p[12], p[13]), u7 = pk2(p[14], p[15]);
    plswap(u0, u2); plswap(u1, u3);          // keys 0..15
    plswap(u4, u6); plswap(u5, u7);          // keys 16..31
    bf16x8 pf0 = frag4(u0, u1, u2, u3);
    bf16x8 pf1 = frag4(u4, u5, u6, u7);

    // ---- O^T += V^T . P^T ----
    __builtin_amdgcn_s_setprio(1);
#pragma unroll
    for (int ks2 = 0; ks2 < 2; ++ks2) {
      bf16x8 pf = ks2 ? pf1 : pf0;
#pragma unroll
      for (int dt = 0; dt < 4; ++dt)
        acc[dt] = __builtin_amdgcn_mfma_f32_32x32x16_bf16(vfrag[dt * 2 + ks2], pf,
                                                          acc[dt], 0, 0, 0);
    }
    __builtin_amdgcn_s_setprio(0);
  }
#undef STAGE

  // ---- epilogue: combine partner l, transpose O^T -> O via LDS, store ----
  float lt = lsum + __shfl_xor(lsum, 32);
  float inv = 1.0f / lt;
  __syncthreads();                           // staging buffers dead now
  float* scr = (float*)ldsb + w * (32 * 33);
  float* ob = O + (int64_t)(b * S_) * 4096;
#pragma unroll
  for (int dt = 0; dt < 4; ++dt) {
#pragma unroll
    for (int r = 0; r < 16; ++r) {
      int crow = (r & 3) + 8 * (r >> 2) + 4 * hi;
      scr[c31 * 33 + crow] = acc[dt][r] * inv;   // scr[col][d']
    }
    asm volatile("" ::: "memory");
#pragma unroll
    for (int rr = 0; rr < 16; ++rr) {
      int col = rr * 2 + hi;
      float val = scr[col * 33 + c31];
      int qi2 = col & 15, hh2 = col >> 4;
      int qq = cc * 32 + (w & 1) * 16 + qi2;
      int h2 = kvh * 4 + (w >> 1) * 2 + hh2;
      ob[(int64_t)qq * 4096 + h2 * 128 + dt * 32 + c31] = val;
    }
    asm volatile("" ::: "memory");
  }
}

extern "C" void kernel_launch(void* const* d_in, const int* in_sizes, int n_in,
                              void* d_out, int out_size, void* d_ws, size_t ws_size,
                              hipStream_t stream) {
  const float* Q   = (const float*)d_in[0];
  const float* K   = (const float*)d_in[1];
  const float* V   = (const float*)d_in[2];
  const float* kvc = (const float*)d_in[3];
  const int*   bi  = (const int*)d_in[4];
  const int*   bo  = (const int*)d_in[5];
  // d_in[6] = attn_bias: exactly the causal mask; applied analytically.

  float* out = (float*)d_out;
  float* kc = out + (int64_t)B_ * S_ * 32 * 128;         // +16777216
  float* vc = kc + (int64_t)128 * 128 * HKV_ * D_;       // +16777216

  short* kimg = (short*)d_ws;                            // 1024 tiles * 8 KB
  short* vimg = kimg + (int64_t)1024 * KTILE_SH;         // 1024 tiles * 8 KB

  // 1) full cache copy (nt stores), both planes
  hipLaunchKernelGGL(copy_kernel, dim3(2048), dim3(256), 0, stream,
                     (const int4v*)kvc, (int4v*)kc);
  // 2) bf16 fragment-linear K/V images + exact fp32 scatter over the copy
  hipLaunchKernelGGL(prep_kernel, dim3(1024), dim3(256), 0, stream,
                     K, V, bi, bo, kc, vc, kimg, vimg);
  // 3) causal GQA attention
  hipLaunchKernelGGL(attn_kernel, dim3(1024), dim3(256), 0, stream,
                     Q, kimg, vimg, out);
}

// Round 11
// 182.839 us; speedup vs baseline: 4.0351x; 1.0984x over previous
//
#include <hip/hip_runtime.h>
#include <hip/hip_bf16.h>
#include <stdint.h>

#define B_ 2
#define S_ 2048
#define HKV_ 8
#define D_ 128

#define KVB 32
#define KTILE_SH 4096        // 8 KB: [ks(8)][hi(2)][key(32)][j(8)] shorts
#define VTILE_SH 4096        // 8 KB: [dt*2+ks2(8)][hi(2)][d(32)][j(8)] shorts
#define LDSBUF 16384         // bytes per staging buffer (K 8 KB + V 8 KB)
#define PLANE4 4194304       // float4 per cache plane

typedef __attribute__((ext_vector_type(8))) short bf16x8;
typedef __attribute__((ext_vector_type(16))) float f32x16;
typedef __attribute__((ext_vector_type(4))) int int4v;

typedef const __attribute__((address_space(1))) void gv_t;
typedef __attribute__((address_space(3))) void lv_t;

__device__ __forceinline__ unsigned pk2(float lo, float hi) {
  unsigned r;
  asm("v_cvt_pk_bf16_f32 %0, %1, %2" : "=v"(r) : "v"(lo), "v"(hi));
  return r;
}
__device__ __forceinline__ void plswap(unsigned& a, unsigned& b) {
  asm volatile("v_permlane32_swap_b32 %0, %1" : "+v"(a), "+v"(b));
}
__device__ __forceinline__ bf16x8 frag4(unsigned a, unsigned b, unsigned c, unsigned d) {
  union { int4v i; bf16x8 v; } u;
  u.i = int4v{(int)a, (int)b, (int)c, (int)d};
  return u.v;
}

// ---------------- cache copy (nt stores: keep LLC for kvc source/images) ----------------

__global__ __launch_bounds__(256)
void copy_kernel(const int4v* __restrict__ src, int4v* __restrict__ dst) {
  const int i = blockIdx.x * 256 + threadIdx.x;   // 524288 threads
#pragma unroll
  for (int j = 0; j < 16; ++j) {
    int64_t idx = (int64_t)j * 524288 + i;
    __builtin_nontemporal_store(src[idx], &dst[idx]);
  }
}

// ------- prep: K,V f32 -> bf16 fragment-linear images + exact fp32 cache scatter -------

__global__ __launch_bounds__(256)
void prep_kernel(const float* __restrict__ K, const float* __restrict__ V,
                 const int* __restrict__ bi, const int* __restrict__ bo,
                 float* __restrict__ kc, float* __restrict__ vc,
                 short* __restrict__ kimg, short* __restrict__ vimg) {
  __shared__ float Vf[KVB * 132];
  const int bid = blockIdx.x;
  const int hg  = bid & 15;          // (b,kvh)
  const int kt  = bid >> 4;          // 0..63
  const int kvh = hg & 7;
  const int b   = hg >> 3;
  const int tid = threadIdx.x;
  const int kv0 = kt * KVB;
  const float* kb = K + (int64_t)b * S_ * 1024 + kvh * 128;
  const float* vb = V + (int64_t)b * S_ * 1024 + kvh * 128;
  short* kimg_t = kimg + (int64_t)(hg * 64 + kt) * KTILE_SH;
  short* vimg_t = vimg + (int64_t)(hg * 64 + kt) * VTILE_SH;
#pragma unroll
  for (int i = 0; i < 4; ++i) {
    int idx = i * 256 + tid;         // 0..1023 float4 slots
    int key = idx >> 5;              // 0..31
    int d0  = (idx & 31) * 4;
    int64_t roff = (int64_t)(kv0 + key) * 1024 + d0;
    float4 kf = *(const float4*)(kb + roff);
    float4 vf = *(const float4*)(vb + roff);
    // cache scatter (exact fp32; overwrites copied slots)
    int tok = b * S_ + kv0 + key;
    int64_t slot = (int64_t)bi[tok] * 128 + bo[tok];
    *(float4*)(kc + slot * 1024 + kvh * 128 + d0) = kf;
    *(float4*)(vc + slot * 1024 + kvh * 128 + d0) = vf;
    // K image, fragment-linear: [d0>>3][key][d0&7]
    unsigned k01 = pk2(kf.x, kf.y), k23 = pk2(kf.z, kf.w);
    int koff = (d0 >> 3) * 256 + key * 8 + (d0 & 7);
    int2 st; st.x = (int)k01; st.y = (int)k23;
    *(int2*)(kimg_t + koff) = st;
    *(float4*)(&Vf[key * 132 + d0]) = vf;
  }
  __syncthreads();
  const int d  = tid & 127;
  const int kg = tid >> 7;           // 0..1, keys k0..k0+15
  const int k0 = kg * 16;
  unsigned uu[8];
#pragma unroll
  for (int i2 = 0; i2 < 8; ++i2)
    uu[i2] = pk2(Vf[(k0 + 2 * i2) * 132 + d], Vf[(k0 + 2 * i2 + 1) * 132 + d]);
  int vbase = ((d >> 5) * 4 + (k0 >> 4) * 2) * 256 + (d & 31) * 8;
  *(int4v*)(vimg_t + vbase)       = int4v{(int)uu[0], (int)uu[1], (int)uu[2], (int)uu[3]};
  *(int4v*)(vimg_t + vbase + 256) = int4v{(int)uu[4], (int)uu[5], (int)uu[6], (int)uu[7]};
}

// ---------------- causal GQA flash attention ----------------
// block = (b,kvh, 32 q rows) x 4 heads; 4 waves. Swapped MFMAs:
//   S^T = mfma(K, Q^T): lane owns col = one (head,q); softmax lane-local.
//   O^T = mfma(V^T, P^T). C/D: col=l&31, row=(r&3)+8*(r>>2)+4*(l>>5).
// Softmax in log2 domain; running shift m carried in the MFMA C-init (s = QK - m).
// REGISTER BUDGET: ~152 unified regs/wave needed. (256,3) = 170 budget: fits.
// (256,4)=128 spills (R9: FETCH 620MB). (256,5)=102 worse (R8: 1.1GB). Keep 3.
// NO s_setprio / NO vfrag hoist: both regressed this lockstep 4-wave structure
// (R10 A/B vs R4: 140 vs 115 us with otherwise-better code).

__global__ __launch_bounds__(256, 3)
void attn_kernel(const float* __restrict__ Q, const short* __restrict__ kimg,
                 const short* __restrict__ vimg, float* __restrict__ O) {
  __shared__ int4v ldsv[2 * LDSBUF / 16];
  char* ldsb = (char*)ldsv;

  const int bid = blockIdx.x;
  const int tid = threadIdx.x;
  const int hg  = bid & 15;          // hg&7 spreads (b,kvh) across XCDs
  const int cc  = 63 - (bid >> 4);   // LPT: longest q-chunks first
  const int kvh = hg & 7;
  const int b   = hg >> 3;

  const int w   = tid >> 6;
  const int l   = tid & 63;
  const int c31 = l & 31;
  const int hi  = l >> 5;
  const int qi  = c31 & 15;
  const int hh  = c31 >> 4;
  const int qoff = cc * 32 + (w & 1) * 16;
  const int qrow = qoff + qi;
  const int h    = kvh * 4 + (w >> 1) * 2 + hh;

  const float qscale = 0.08838834764831845f * 1.4426950408889634f; // 1/sqrt(D)*log2e

  // ---- Q fragments (B-frag: col = (head,q), k = d-slice) ----
  const float* qp = Q + ((int64_t)(b * S_ + qrow)) * 4096 + h * 128;
  bf16x8 qf[8];
#pragma unroll
  for (int ks = 0; ks < 8; ++ks) {
    int d0 = ks * 16 + hi * 8;
    float4 x = *(const float4*)(qp + d0);
    float4 y = *(const float4*)(qp + d0 + 4);
    qf[ks] = frag4(pk2(x.x * qscale, x.y * qscale), pk2(x.z * qscale, x.w * qscale),
                   pk2(y.x * qscale, y.y * qscale), pk2(y.z * qscale, y.w * qscale));
  }

  f32x16 acc[4];
#pragma unroll
  for (int dt = 0; dt < 4; ++dt)
#pragma unroll
    for (int r = 0; r < 16; ++r) acc[dt][r] = 0.f;
  float m = 0.f, lsum = 0.f;    // log2-domain shift; m=0 safe (defer-max bounds p<=2^11)

  const int nkt = cc + 1;
  const short* kimg_b = kimg + (int64_t)(hg * 64) * KTILE_SH;
  const short* vimg_b = vimg + (int64_t)(hg * 64) * VTILE_SH;

#define STAGE(KT, BUF)                                                           \
  do {                                                                           \
    const short* kg_ = kimg_b + (int64_t)(KT) * KTILE_SH;                        \
    const short* vg_ = vimg_b + (int64_t)(KT) * VTILE_SH;                        \
    char* kd_ = ldsb + (BUF) * LDSBUF;                                           \
    char* vd_ = kd_ + 8192;                                                      \
    _Pragma("unroll")                                                            \
    for (int i_ = 0; i_ < 2; ++i_) {                                             \
      int u_ = i_ * 256 + w * 64;                                                \
      __builtin_amdgcn_global_load_lds((gv_t*)(const void*)(kg_ + (u_ + l) * 8), \
                                       (lv_t*)(void*)(kd_ + u_ * 16), 16, 0, 0); \
      __builtin_amdgcn_global_load_lds((gv_t*)(const void*)(vg_ + (u_ + l) * 8), \
                                       (lv_t*)(void*)(vd_ + u_ * 16), 16, 0, 0); \
    }                                                                            \
  } while (0)

  STAGE(0, 0);

  for (int kt = 0; kt < nkt; ++kt) {
    __syncthreads();                  // buf[kt&1] ready; buf[kt&1 ^1] free
    const int cur = kt & 1;
    if (kt + 1 < nkt) STAGE(kt + 1, cur ^ 1);
    const char* kfr = ldsb + cur * LDSBUF + hi * 512 + c31 * 16;
    const char* vfr = kfr + 8192;
    const int kv0 = kt * KVB;

    // ---- S^T = K . Q^T, C-init = -m (folds softmax shift into MFMA) ----
    const float negm = -m;
    f32x16 s;
#pragma unroll
    for (int r = 0; r < 16; ++r) s[r] = negm;
#pragma unroll
    for (int ks = 0; ks < 8; ++ks) {
      bf16x8 kf = *(const bf16x8*)(kfr + ks * 1024);
      s = __builtin_amdgcn_mfma_f32_32x32x16_bf16(kf, qf[ks], s, 0, 0, 0);
    }

    // ---- causal mask (boundary tiles only) ----
    if (kv0 + 31 > qoff) {
#pragma unroll
      for (int r = 0; r < 16; ++r) {
        int key = kv0 + (r & 3) + 8 * (r >> 2) + 4 * hi;
        if (key > qrow) s[r] = -1e30f;
      }
    }

    // ---- lane-local online softmax (log2 domain, defer-max THR=11) ----
    float a0 = fmaxf(s[0], s[1]),   a1 = fmaxf(s[2], s[3]);
    float a2 = fmaxf(s[4], s[5]),   a3 = fmaxf(s[6], s[7]);
    float a4 = fmaxf(s[8], s[9]),   a5 = fmaxf(s[10], s[11]);
    float a6 = fmaxf(s[12], s[13]), a7 = fmaxf(s[14], s[15]);
    a0 = fmaxf(a0, a1); a2 = fmaxf(a2, a3); a4 = fmaxf(a4, a5); a6 = fmaxf(a6, a7);
    float qm = fmaxf(fmaxf(a0, a2), fmaxf(a4, a6));   // = tile max - m
    qm = fmaxf(qm, __shfl_xor(qm, 32));               // partner lane (same q)
    if (__any(qm > 11.0f)) {
      float dsh = fmaxf(qm, 0.f);
      float al = exp2f(-dsh);
      m += dsh; lsum *= al;
#pragma unroll
      for (int r = 0; r < 16; ++r) s[r] -= dsh;
#pragma unroll
      for (int dt = 0; dt < 4; ++dt)
#pragma unroll
        for (int r = 0; r < 16; ++r) acc[dt][r] *= al;
    }
    float p[16];
#pragma unroll
    for (int r = 0; r < 16; ++r) p[r] = exp2f(s[r]);
    float b0 = (p[0] + p[1]) + (p[2] + p[3]);
    float b1 = (p[4] + p[5]) + (p[6] + p[7]);
    float b2 = (p[8] + p[9]) + (p[10] + p[11]);
    float b3 = (p[12] + p[13]) + (p[14] + p[15]);
    lsum += (b0 + b1) + (b2 + b3);

    // ---- P -> bf16 B-frags via cvt_pk + permlane32_swap (no LDS) ----
    unsigned u0 = pk2(p[0], p[1]),   u1 = pk2(p[2], p[3]);
    unsigned u2 = pk2(p[4], p[5]),   u3 = pk2(p[6], p[7]);
    unsigned u4 = pk2(p[8], p[9]),   u5 = pk2(p[10], p[11]);
    unsigned u6 = pk2(p[12], p[13]), u7 = pk2(p[14], p[15]);
    plswap(u0, u2); plswap(u1, u3);          // keys 0..15
    plswap(u4, u6); plswap(u5, u7);          // keys 16..31
    bf16x8 pf0 = frag4(u0, u1, u2, u3);
    bf16x8 pf1 = frag4(u4, u5, u6, u7);

    // ---- O^T += V^T . P^T (V frags read in-loop: compiler interleaves) ----
#pragma unroll
    for (int ks2 = 0; ks2 < 2; ++ks2) {
      bf16x8 pf = ks2 ? pf1 : pf0;
#pragma unroll
      for (int dt = 0; dt < 4; ++dt) {
        bf16x8 vf = *(const bf16x8*)(vfr + (dt * 2 + ks2) * 1024);
        acc[dt] = __builtin_amdgcn_mfma_f32_32x32x16_bf16(vf, pf, acc[dt], 0, 0, 0);
      }
    }
  }
#undef STAGE

  // ---- epilogue: combine partner l, transpose O^T -> O via LDS, store ----
  float lt = lsum + __shfl_xor(lsum, 32);
  float inv = 1.0f / lt;
  __syncthreads();                           // staging buffers dead now
  float* scr = (float*)ldsb + w * (32 * 33);
  float* ob = O + (int64_t)(b * S_) * 4096;
#pragma unroll
  for (int dt = 0; dt < 4; ++dt) {
#pragma unroll
    for (int r = 0; r < 16; ++r) {
      int crow = (r & 3) + 8 * (r >> 2) + 4 * hi;
      scr[c31 * 33 + crow] = acc[dt][r] * inv;   // scr[col][d']
    }
    asm volatile("" ::: "memory");
#pragma unroll
    for (int rr = 0; rr < 16; ++rr) {
      int col = rr * 2 + hi;
      float val = scr[col * 33 + c31];
      int qi2 = col & 15, hh2 = col >> 4;
      int qq = cc * 32 + (w & 1) * 16 + qi2;
      int h2 = kvh * 4 + (w >> 1) * 2 + hh2;
      ob[(int64_t)qq * 4096 + h2 * 128 + dt * 32 + c31] = val;
    }
    asm volatile("" ::: "memory");
  }
}

extern "C" void kernel_launch(void* const* d_in, const int* in_sizes, int n_in,
                              void* d_out, int out_size, void* d_ws, size_t ws_size,
                              hipStream_t stream) {
  const float* Q   = (const float*)d_in[0];
  const float* K   = (const float*)d_in[1];
  const float* V   = (const float*)d_in[2];
  const float* kvc = (const float*)d_in[3];
  const int*   bi  = (const int*)d_in[4];
  const int*   bo  = (const int*)d_in[5];
  // d_in[6] = attn_bias: exactly the causal mask; applied analytically.

  float* out = (float*)d_out;
  float* kc = out + (int64_t)B_ * S_ * 32 * 128;         // +16777216
  float* vc = kc + (int64_t)128 * 128 * HKV_ * D_;       // +16777216

  short* kimg = (short*)d_ws;                            // 1024 tiles * 8 KB
  short* vimg = kimg + (int64_t)1024 * KTILE_SH;         // 1024 tiles * 8 KB

  // 1) full cache copy (nt stores), both planes
  hipLaunchKernelGGL(copy_kernel, dim3(2048), dim3(256), 0, stream,
                     (const int4v*)kvc, (int4v*)kc);
  // 2) bf16 fragment-linear K/V images + exact fp32 scatter over the copy
  hipLaunchKernelGGL(prep_kernel, dim3(1024), dim3(256), 0, stream,
                     K, V, bi, bo, kc, vc, kimg, vimg);
  // 3) causal GQA attention
  hipLaunchKernelGGL(attn_kernel, dim3(1024), dim3(256), 0, stream,
                     Q, kimg, vimg, out);
}

// Round 12
// 175.005 us; speedup vs baseline: 4.2158x; 1.0448x over previous
//
#include <hip/hip_runtime.h>
#include <hip/hip_bf16.h>
#include <stdint.h>

#define B_ 2
#define S_ 2048
#define HKV_ 8
#define D_ 128

#define KVB 32
#define KTILE_SH 4096        // 8 KB: [ks(8)][hi(2)][key(32)][j(8)] shorts
#define VTILE_SH 4096        // 8 KB: [dt*2+ks2(8)][hi(2)][d(32)][j(8)] shorts
#define LDSBUF 16384         // bytes per staging buffer (K 8 KB + V 8 KB)
#define NATTN 1024
#define NSCAT 256            // scatter tail blocks in attn grid
#define NPREP 1024
#define NCOPY 2048

typedef __attribute__((ext_vector_type(8))) short bf16x8;
typedef __attribute__((ext_vector_type(16))) float f32x16;
typedef __attribute__((ext_vector_type(4))) int int4v;

typedef const __attribute__((address_space(1))) void gv_t;
typedef __attribute__((address_space(3))) void lv_t;

__device__ __forceinline__ unsigned pk2(float lo, float hi) {
  unsigned r;
  asm("v_cvt_pk_bf16_f32 %0, %1, %2" : "=v"(r) : "v"(lo), "v"(hi));
  return r;
}
__device__ __forceinline__ void plswap(unsigned& a, unsigned& b) {
  asm volatile("v_permlane32_swap_b32 %0, %1" : "+v"(a), "+v"(b));
}
__device__ __forceinline__ bf16x8 frag4(unsigned a, unsigned b, unsigned c, unsigned d) {
  union { int4v i; bf16x8 v; } u;
  u.i = int4v{(int)a, (int)b, (int)c, (int)d};
  return u.v;
}

// ------- fused A: bf16 fragment-linear images (blocks 0..1023) + cache copy (tail) -------

__global__ __launch_bounds__(256)
void prepcopy_kernel(const float* __restrict__ K, const float* __restrict__ V,
                     short* __restrict__ kimg, short* __restrict__ vimg,
                     const int4v* __restrict__ kvc, int4v* __restrict__ cdst) {
  __shared__ float Vf[KVB * 132];
  const int bid = blockIdx.x;
  const int tid = threadIdx.x;

  if (bid >= NPREP) {
    // ---- full cache copy (nt stores), 2048 blocks ----
    const int i = (bid - NPREP) * 256 + tid;     // 524288 threads
#pragma unroll
    for (int j = 0; j < 16; ++j) {
      int64_t idx = (int64_t)j * 524288 + i;
      __builtin_nontemporal_store(kvc[idx], &cdst[idx]);
    }
    return;
  }

  const int hg  = bid & 15;          // (b,kvh)
  const int kt  = bid >> 4;          // 0..63
  const int kvh = hg & 7;
  const int b   = hg >> 3;
  const int kv0 = kt * KVB;
  const float* kb = K + (int64_t)b * S_ * 1024 + kvh * 128;
  const float* vb = V + (int64_t)b * S_ * 1024 + kvh * 128;
  short* kimg_t = kimg + (int64_t)(hg * 64 + kt) * KTILE_SH;
  short* vimg_t = vimg + (int64_t)(hg * 64 + kt) * VTILE_SH;
#pragma unroll
  for (int i = 0; i < 4; ++i) {
    int idx = i * 256 + tid;         // 0..1023 float4 slots
    int key = idx >> 5;              // 0..31
    int d0  = (idx & 31) * 4;
    int64_t roff = (int64_t)(kv0 + key) * 1024 + d0;
    float4 kf = *(const float4*)(kb + roff);
    float4 vf = *(const float4*)(vb + roff);
    // K image, fragment-linear: [d0>>3][key][d0&7]
    unsigned k01 = pk2(kf.x, kf.y), k23 = pk2(kf.z, kf.w);
    int koff = (d0 >> 3) * 256 + key * 8 + (d0 & 7);
    int2 st; st.x = (int)k01; st.y = (int)k23;
    *(int2*)(kimg_t + koff) = st;
    *(float4*)(&Vf[key * 132 + d0]) = vf;
  }
  __syncthreads();
  const int d  = tid & 127;
  const int kg = tid >> 7;           // 0..1, keys k0..k0+15
  const int k0 = kg * 16;
  unsigned uu[8];
#pragma unroll
  for (int i2 = 0; i2 < 8; ++i2)
    uu[i2] = pk2(Vf[(k0 + 2 * i2) * 132 + d], Vf[(k0 + 2 * i2 + 1) * 132 + d]);
  int vbase = ((d >> 5) * 4 + (k0 >> 4) * 2) * 256 + (d & 31) * 8;
  *(int4v*)(vimg_t + vbase)       = int4v{(int)uu[0], (int)uu[1], (int)uu[2], (int)uu[3]};
  *(int4v*)(vimg_t + vbase + 256) = int4v{(int)uu[4], (int)uu[5], (int)uu[6], (int)uu[7]};
}

// ------- fused B: causal GQA attention (blocks 0..1023) + cache scatter (tail) -------
// attn: block = (b,kvh, 32 q rows) x 4 heads; 4 waves. Swapped MFMAs:
//   S^T = mfma(K, Q^T): lane owns col = one (head,q); softmax lane-local.
//   O^T = mfma(V^T, P^T). C/D: col=l&31, row=(r&3)+8*(r>>2)+4*(l>>5).
// 3-buffer staging, counted vmcnt: s_waitcnt vmcnt(4) + raw s_barrier keeps the
// next tile's 4 global_load_lds in flight across the barrier (T4). Last tile
// drains vmcnt(0). STAGE(t+2) issued after the barrier (buf t-1 provably free).
// REGISTER BUDGET: (256,3)=170 fits (~152 used). (256,4) spills (R9). No
// setprio / no vfrag hoist (R10 regression, lockstep structure).

__global__ __launch_bounds__(256, 3)
void attn_kernel(const float* __restrict__ Q, const short* __restrict__ kimg,
                 const short* __restrict__ vimg, float* __restrict__ O,
                 const int4v* __restrict__ key4, const int4v* __restrict__ val4,
                 const int* __restrict__ bi, const int* __restrict__ bo,
                 int4v* __restrict__ kc4, int4v* __restrict__ vc4) {
  __shared__ int4v ldsv[3 * LDSBUF / 16];
  char* ldsb = (char*)ldsv;

  const int bid = blockIdx.x;
  const int tid = threadIdx.x;

  if (bid >= NATTN) {
    // ---- cache scatter tail (67 MB total: ~1% of BW, can't starve attn) ----
    const int base = (bid - NATTN) * 256 + tid;    // 65536 threads
#pragma unroll
    for (int i = 0; i < 16; ++i) {
      int idx = base + i * 65536;                  // 1,048,576 float4 per plane
      int t = idx >> 8;
      int rem = idx & 255;
      int64_t slot = (int64_t)bi[t] * 128 + bo[t];
      kc4[slot * 256 + rem] = key4[(int64_t)t * 256 + rem];
      vc4[slot * 256 + rem] = val4[(int64_t)t * 256 + rem];
    }
    return;
  }

  const int hg  = bid & 15;          // hg&7 spreads (b,kvh) across XCDs
  const int cc  = 63 - (bid >> 4);   // LPT: longest q-chunks first
  const int kvh = hg & 7;
  const int b   = hg >> 3;

  const int w   = tid >> 6;
  const int l   = tid & 63;
  const int c31 = l & 31;
  const int hi  = l >> 5;
  const int qi  = c31 & 15;
  const int hh  = c31 >> 4;
  const int qoff = cc * 32 + (w & 1) * 16;
  const int qrow = qoff + qi;
  const int h    = kvh * 4 + (w >> 1) * 2 + hh;

  const float qscale = 0.08838834764831845f * 1.4426950408889634f; // 1/sqrt(D)*log2e

  // ---- Q fragments (B-frag: col = (head,q), k = d-slice) ----
  const float* qp = Q + ((int64_t)(b * S_ + qrow)) * 4096 + h * 128;
  bf16x8 qf[8];
#pragma unroll
  for (int ks = 0; ks < 8; ++ks) {
    int d0 = ks * 16 + hi * 8;
    float4 x = *(const float4*)(qp + d0);
    float4 y = *(const float4*)(qp + d0 + 4);
    qf[ks] = frag4(pk2(x.x * qscale, x.y * qscale), pk2(x.z * qscale, x.w * qscale),
                   pk2(y.x * qscale, y.y * qscale), pk2(y.z * qscale, y.w * qscale));
  }

  f32x16 acc[4];
#pragma unroll
  for (int dt = 0; dt < 4; ++dt)
#pragma unroll
    for (int r = 0; r < 16; ++r) acc[dt][r] = 0.f;
  float m = 0.f, lsum = 0.f;    // log2-domain shift; m=0 safe (defer-max bounds p<=2^11)

  const int nkt = cc + 1;
  const short* kimg_b = kimg + (int64_t)(hg * 64) * KTILE_SH;
  const short* vimg_b = vimg + (int64_t)(hg * 64) * VTILE_SH;

#define STAGE(KT, BUF)                                                           \
  do {                                                                           \
    const short* kg_ = kimg_b + (int64_t)(KT) * KTILE_SH;                        \
    const short* vg_ = vimg_b + (int64_t)(KT) * VTILE_SH;                        \
    char* kd_ = ldsb + (BUF) * LDSBUF;                                           \
    char* vd_ = kd_ + 8192;                                                      \
    _Pragma("unroll")                                                            \
    for (int i_ = 0; i_ < 2; ++i_) {                                             \
      int u_ = i_ * 256 + w * 64;                                                \
      __builtin_amdgcn_global_load_lds((gv_t*)(const void*)(kg_ + (u_ + l) * 8), \
                                       (lv_t*)(void*)(kd_ + u_ * 16), 16, 0, 0); \
      __builtin_amdgcn_global_load_lds((gv_t*)(const void*)(vg_ + (u_ + l) * 8), \
                                       (lv_t*)(void*)(vd_ + u_ * 16), 16, 0, 0); \
    }                                                                            \
  } while (0)

  STAGE(0, 0);
  if (nkt > 1) STAGE(1, 1);

  for (int kt = 0; kt < nkt; ++kt) {
    // counted wait: own STAGE(kt) retired (4 loads of STAGE(kt+1) may fly on)
    if (kt + 1 < nkt) asm volatile("s_waitcnt vmcnt(4)" ::: "memory");
    else              asm volatile("s_waitcnt vmcnt(0)" ::: "memory");
    __builtin_amdgcn_s_barrier();
    asm volatile("" ::: "memory");   // fence: no ds_read hoists above barrier
    if (kt + 2 < nkt) STAGE(kt + 2, (kt + 2) % 3);
    const char* kfr = ldsb + (kt % 3) * LDSBUF + hi * 512 + c31 * 16;
    const char* vfr = kfr + 8192;
    const int kv0 = kt * KVB;

    // ---- S^T = K . Q^T, C-init = -m (folds softmax shift into MFMA) ----
    const float negm = -m;
    f32x16 s;
#pragma unroll
    for (int r = 0; r < 16; ++r) s[r] = negm;
#pragma unroll
    for (int ks = 0; ks < 8; ++ks) {
      bf16x8 kf = *(const bf16x8*)(kfr + ks * 1024);
      s = __builtin_amdgcn_mfma_f32_32x32x16_bf16(kf, qf[ks], s, 0, 0, 0);
    }

    // ---- causal mask (boundary tiles only) ----
    if (kv0 + 31 > qoff) {
#pragma unroll
      for (int r = 0; r < 16; ++r) {
        int key = kv0 + (r & 3) + 8 * (r >> 2) + 4 * hi;
        if (key > qrow) s[r] = -1e30f;
      }
    }

    // ---- lane-local online softmax (log2 domain, defer-max THR=11) ----
    float a0 = fmaxf(s[0], s[1]),   a1 = fmaxf(s[2], s[3]);
    float a2 = fmaxf(s[4], s[5]),   a3 = fmaxf(s[6], s[7]);
    float a4 = fmaxf(s[8], s[9]),   a5 = fmaxf(s[10], s[11]);
    float a6 = fmaxf(s[12], s[13]), a7 = fmaxf(s[14], s[15]);
    a0 = fmaxf(a0, a1); a2 = fmaxf(a2, a3); a4 = fmaxf(a4, a5); a6 = fmaxf(a6, a7);
    float qm = fmaxf(fmaxf(a0, a2), fmaxf(a4, a6));   // = tile max - m
    qm = fmaxf(qm, __shfl_xor(qm, 32));               // partner lane (same q)
    if (__any(qm > 11.0f)) {
      float dsh = fmaxf(qm, 0.f);
      float al = exp2f(-dsh);
      m += dsh; lsum *= al;
#pragma unroll
      for (int r = 0; r < 16; ++r) s[r] -= dsh;
#pragma unroll
      for (int dt = 0; dt < 4; ++dt)
#pragma unroll
        for (int r = 0; r < 16; ++r) acc[dt][r] *= al;
    }
    float p[16];
#pragma unroll
    for (int r = 0; r < 16; ++r) p[r] = exp2f(s[r]);
    float b0 = (p[0] + p[1]) + (p[2] + p[3]);
    float b1 = (p[4] + p[5]) + (p[6] + p[7]);
    float b2 = (p[8] + p[9]) + (p[10] + p[11]);
    float b3 = (p[12] + p[13]) + (p[14] + p[15]);
    lsum += (b0 + b1) + (b2 + b3);

    // ---- P -> bf16 B-frags via cvt_pk + permlane32_swap (no LDS) ----
    unsigned u0 = pk2(p[0], p[1]),   u1 = pk2(p[2], p[3]);
    unsigned u2 = pk2(p[4], p[5]),   u3 = pk2(p[6], p[7]);
    unsigned u4 = pk2(p[8], p[9]),   u5 = pk2(p[10], p[11]);
    unsigned u6 = pk2(p[12], p[13]), u7 = pk2(p[14], p[15]);
    plswap(u0, u2); plswap(u1, u3);          // keys 0..15
    plswap(u4, u6); plswap(u5, u7);          // keys 16..31
    bf16x8 pf0 = frag4(u0, u1, u2, u3);
    bf16x8 pf1 = frag4(u4, u5, u6, u7);

    // ---- O^T += V^T . P^T (V frags read in-loop: compiler interleaves) ----
#pragma unroll
    for (int ks2 = 0; ks2 < 2; ++ks2) {
      bf16x8 pf = ks2 ? pf1 : pf0;
#pragma unroll
      for (int dt = 0; dt < 4; ++dt) {
        bf16x8 vf = *(const bf16x8*)(vfr + (dt * 2 + ks2) * 1024);
        acc[dt] = __builtin_amdgcn_mfma_f32_32x32x16_bf16(vf, pf, acc[dt], 0, 0, 0);
      }
    }
  }
#undef STAGE

  // ---- epilogue: combine partner l, transpose O^T -> O via LDS, store ----
  float lt = lsum + __shfl_xor(lsum, 32);
  float inv = 1.0f / lt;
  __syncthreads();                           // staging buffers dead now
  float* scr = (float*)ldsb + w * (32 * 33);
  float* ob = O + (int64_t)(b * S_) * 4096;
#pragma unroll
  for (int dt = 0; dt < 4; ++dt) {
#pragma unroll
    for (int r = 0; r < 16; ++r) {
      int crow = (r & 3) + 8 * (r >> 2) + 4 * hi;
      scr[c31 * 33 + crow] = acc[dt][r] * inv;   // scr[col][d']
    }
    asm volatile("" ::: "memory");
#pragma unroll
    for (int rr = 0; rr < 16; ++rr) {
      int col = rr * 2 + hi;
      float val = scr[col * 33 + c31];
      int qi2 = col & 15, hh2 = col >> 4;
      int qq = cc * 32 + (w & 1) * 16 + qi2;
      int h2 = kvh * 4 + (w >> 1) * 2 + hh2;
      ob[(int64_t)qq * 4096 + h2 * 128 + dt * 32 + c31] = val;
    }
    asm volatile("" ::: "memory");
  }
}

extern "C" void kernel_launch(void* const* d_in, const int* in_sizes, int n_in,
                              void* d_out, int out_size, void* d_ws, size_t ws_size,
                              hipStream_t stream) {
  const float* Q   = (const float*)d_in[0];
  const float* K   = (const float*)d_in[1];
  const float* V   = (const float*)d_in[2];
  const float* kvc = (const float*)d_in[3];
  const int*   bi  = (const int*)d_in[4];
  const int*   bo  = (const int*)d_in[5];
  // d_in[6] = attn_bias: exactly the causal mask; applied analytically.

  float* out = (float*)d_out;
  float* kc = out + (int64_t)B_ * S_ * 32 * 128;         // +16777216
  float* vc = kc + (int64_t)128 * 128 * HKV_ * D_;       // +16777216

  short* kimg = (short*)d_ws;                            // 1024 tiles * 8 KB
  short* vimg = kimg + (int64_t)1024 * KTILE_SH;         // 1024 tiles * 8 KB

  // A) fragment-linear K/V images (first) + full cache copy (tail)
  hipLaunchKernelGGL(prepcopy_kernel, dim3(NPREP + NCOPY), dim3(256), 0, stream,
                     K, V, kimg, vimg, (const int4v*)kvc, (int4v*)kc);
  // B) attention (LPT-ordered, first) + cache scatter (tail)
  hipLaunchKernelGGL(attn_kernel, dim3(NATTN + NSCAT), dim3(256), 0, stream,
                     Q, kimg, vimg, out,
                     (const int4v*)K, (const int4v*)V, bi, bo,
                     (int4v*)kc, (int4v*)vc);
}